// Round 1
// baseline (688.379 us; speedup 1.0000x reference)
//
#include <hip/hip_runtime.h>
#include <math.h>

// Problem constants (from reference setup_inputs)
#define B_    4
#define L_    4092
#define H_    8
#define DH    64
#define DM    512        // H_*DH
#define WS_   12
#define STEP_ 6
#define NW    681        // (L - OV) / STEP
#define EPS_  1e-5f

#define Z_ELEMS    (B_*L_*DM)              // 8,380,416
#define ATTN_ELEMS (B_*H_*NW*WS_*WS_)      // 3,138,048
// workspace: ow [B,H,NW,WS,DH] fp32 = 66,945,024 bytes (assumes ws_size >= 67MB)

// ---------------------------------------------------------------------------
// Kernel A: per-(b,h,n) window attention.
//   - stage Wq/Wk/Wv in LDS (stride 65 -> (e+d)%32 banking, 2-way = free)
//   - project Q,K,V [12,64] into LDS
//   - scores 12x12, softmax -> write attn to d_out
//   - P @ V -> ow workspace
// ---------------------------------------------------------------------------
__global__ __launch_bounds__(256) void attn_win_kernel(
    const float* __restrict__ q, const float* __restrict__ k, const float* __restrict__ v,
    const float* __restrict__ Wq, const float* __restrict__ Wk, const float* __restrict__ Wv,
    float* __restrict__ attn_out, float* __restrict__ ow_ws)
{
    const int n = blockIdx.x;
    const int h = blockIdx.y;
    const int b = blockIdx.z;
    const int t = threadIdx.x;

    __shared__ float Wq_s[64*65];
    __shared__ float Wk_s[64*65];
    __shared__ float Wv_s[64*65];
    __shared__ float Qs[WS_*65];
    __shared__ float Ks[WS_*65];
    __shared__ float Vs[WS_*65];
    __shared__ float P[WS_][WS_+1];

    // stage weight matrices (coalesced global reads)
    for (int m = t; m < 64*64; m += 256) {
        int r = m >> 6, c = m & 63;
        Wq_s[r*65+c] = Wq[m];
        Wk_s[r*65+c] = Wk[m];
        Wv_s[r*65+c] = Wv[m];
    }
    __syncthreads();

    // projections: Q[w][e] = sum_d q[b, n*6+w, h, d] * Wq[e][d]  (x @ W^T)
    for (int j = 0; j < 3; ++j) {
        int i = t + j*256;           // i in [0,768)
        int w = i >> 6, e = i & 63;  // per wave: one w, e = lane
        int l = n*STEP_ + w;
        const float* qr = q + (((size_t)b*L_ + l)*H_ + h)*DH;
        const float* kr = k + (((size_t)b*L_ + l)*H_ + h)*DH;
        const float* vr = v + (((size_t)b*L_ + l)*H_ + h)*DH;
        float aq = 0.f, ak = 0.f, av = 0.f;
        #pragma unroll 8
        for (int d = 0; d < 64; ++d) {
            float xq = qr[d], xk = kr[d], xv = vr[d];
            aq = fmaf(xq, Wq_s[e*65+d], aq);
            ak = fmaf(xk, Wk_s[e*65+d], ak);
            av = fmaf(xv, Wv_s[e*65+d], av);
        }
        Qs[w*65+e] = aq;
        Ks[w*65+e] = ak;
        Vs[w*65+e] = av;
    }
    __syncthreads();

    // scores S[wq][wk] = (Q[wq] . K[wk]) / 8
    if (t < WS_*WS_) {
        int wq = t / WS_, wk = t % WS_;
        float s = 0.f;
        #pragma unroll 8
        for (int d = 0; d < 64; ++d)
            s = fmaf(Qs[wq*65+d], Ks[wk*65+d], s);
        P[wq][wk] = s * 0.125f;
    }
    __syncthreads();

    // softmax per row (12 rows, tiny)
    if (t < WS_) {
        float mx = -1e30f;
        #pragma unroll
        for (int j = 0; j < WS_; ++j) mx = fmaxf(mx, P[t][j]);
        float sum = 0.f;
        #pragma unroll
        for (int j = 0; j < WS_; ++j) { float e = expf(P[t][j] - mx); P[t][j] = e; sum += e; }
        float inv = 1.0f / sum;
        #pragma unroll
        for (int j = 0; j < WS_; ++j) P[t][j] *= inv;
    }
    __syncthreads();

    // write attn probabilities
    if (t < WS_*WS_) {
        attn_out[(((size_t)b*H_ + h)*NW + n)*(WS_*WS_) + t] = P[t / WS_][t % WS_];
    }

    // ow[w][e] = sum_k P[w][k] * V[k][e]  -> workspace
    for (int j = 0; j < 3; ++j) {
        int i = t + j*256;
        int w = i >> 6, e = i & 63;
        float acc = 0.f;
        #pragma unroll
        for (int kk = 0; kk < WS_; ++kk)
            acc = fmaf(P[w][kk], Vs[kk*65+e], acc);
        ow_ws[((((size_t)b*H_ + h)*NW + n)*WS_ + w)*DH + e] = acc;
    }
}

// ---------------------------------------------------------------------------
// Kernel B: gather overlap-add (<=2 contributing windows per row, deterministic,
// no atomics) + 1/cnt + residual + LayerNorm. One block per (b,l) row.
// ---------------------------------------------------------------------------
__global__ __launch_bounds__(256) void oadd_ln_kernel(
    const float* __restrict__ ow_ws, const float* __restrict__ q,
    const float* __restrict__ gamma, const float* __restrict__ beta,
    float* __restrict__ z)
{
    const int row = blockIdx.x;          // b*L + l
    const int b = row / L_;
    const int l = row - b*L_;
    const int t = threadIdx.x;

    const int nA = l / STEP_;            // window ending later (may be == NW, invalid)
    const int nB = nA - 1;               // earlier window (may be -1, invalid)
    const bool vA = (nA < NW);
    const bool vB = (nB >= 0);
    const float cntInv = 1.0f / (float)((vA ? 1 : 0) + (vB ? 1 : 0));

    float x[2];
    #pragma unroll
    for (int j = 0; j < 2; ++j) {
        int c = t + j*256;               // c in [0,512)
        int h = c >> 6, e = c & 63;
        float s = 0.f;
        if (vA) {
            int w = l - nA*STEP_;
            s += ow_ws[((((size_t)b*H_ + h)*NW + nA)*WS_ + w)*DH + e];
        }
        if (vB) {
            int w = l - nB*STEP_;
            s += ow_ws[((((size_t)b*H_ + h)*NW + nB)*WS_ + w)*DH + e];
        }
        x[j] = s * cntInv + q[(size_t)row*DM + c];
    }

    // block reduction for mean and mean-of-squares
    float s1 = x[0] + x[1];
    float s2 = x[0]*x[0] + x[1]*x[1];
    #pragma unroll
    for (int off = 32; off > 0; off >>= 1) {
        s1 += __shfl_down(s1, off);
        s2 += __shfl_down(s2, off);
    }
    __shared__ float r1[4], r2[4];
    const int wid = t >> 6;
    if ((t & 63) == 0) { r1[wid] = s1; r2[wid] = s2; }
    __syncthreads();
    s1 = r1[0] + r1[1] + r1[2] + r1[3];
    s2 = r2[0] + r2[1] + r2[2] + r2[3];
    const float mu  = s1 * (1.0f/512.0f);
    const float var = s2 * (1.0f/512.0f) - mu*mu;
    const float inv = 1.0f / sqrtf(var + EPS_);

    #pragma unroll
    for (int j = 0; j < 2; ++j) {
        int c = t + j*256;
        z[(size_t)row*DM + c] = (x[j] - mu) * inv * gamma[c] + beta[c];
    }
}

extern "C" void kernel_launch(void* const* d_in, const int* in_sizes, int n_in,
                              void* d_out, int out_size, void* d_ws, size_t ws_size,
                              hipStream_t stream) {
    const float* q     = (const float*)d_in[0];
    const float* k     = (const float*)d_in[1];
    const float* v     = (const float*)d_in[2];
    const float* Wq    = (const float*)d_in[3];
    const float* Wk    = (const float*)d_in[4];
    const float* Wv    = (const float*)d_in[5];
    const float* gamma = (const float*)d_in[6];
    const float* beta  = (const float*)d_in[7];

    float* z    = (float*)d_out;
    float* attn = (float*)d_out + Z_ELEMS;
    float* ow   = (float*)d_ws;   // B*H*NW*WS*DH fp32 = ~67 MB

    attn_win_kernel<<<dim3(NW, H_, B_), 256, 0, stream>>>(q, k, v, Wq, Wk, Wv, attn, ow);
    oadd_ln_kernel<<<B_*L_, 256, 0, stream>>>(ow, q, gamma, beta, z);
}

// Round 2
// 353.994 us; speedup vs baseline: 1.9446x; 1.9446x over previous
//
#include <hip/hip_runtime.h>
#include <math.h>

// Problem constants (from reference setup_inputs)
#define B_    4
#define L_    4092
#define H_    8
#define DH    64
#define DM    512        // H_*DH
#define WS_   12
#define STEP_ 6
#define NW    681        // (L - OV) / STEP
#define EPS_  1e-5f

#define Z_ELEMS    (B_*L_*DM)              // 8,380,416
#define WPB   16                            // windows per block
#define NSEG  ((NW + WPB - 1) / WPB)        // 43

// ---------------------------------------------------------------------------
// Fused window-attention kernel.
// Block = 192 threads = 3 waves; wave p handles projection type p (q/k/v).
// Lane e caches W_p[e][0..63] in 64 VGPRs (loaded once per block from L2).
// Each block iterates WPB consecutive windows for one (b,h):
//   stage X (12x64 x3) -> LDS   (coalesced float4)
//   project  (FMA w/ reg W, X via wave-uniform LDS broadcast b128 reads)
//   scores 12x12 -> softmax -> attn out
//   P@V -> ow workspace
// ---------------------------------------------------------------------------
__global__ __launch_bounds__(192) void fused_attn_kernel(
    const float* __restrict__ q, const float* __restrict__ k, const float* __restrict__ v,
    const float* __restrict__ Wq, const float* __restrict__ Wk, const float* __restrict__ Wv,
    float* __restrict__ attn_out, float* __restrict__ ow_ws)
{
    const int seg = blockIdx.x;
    const int h   = blockIdx.y;
    const int b   = blockIdx.z;
    const int t   = threadIdx.x;
    const int lane = t & 63;
    const int wave = t >> 6;            // 0,1,2 -> q,k,v

    __shared__ alignas(16) float Xs[3][WS_][64];    // raw input rows
    __shared__ alignas(16) float Ps[3][WS_][68];    // projected Q,K,V (68: 16B-aligned rows, bank-spread)
    __shared__ float P[WS_][WS_ + 1];               // scores/probs

    // --- cache W row in registers: lane e of wave p holds W_p[e][:] ---
    const float* __restrict__ Wsel = (wave == 0) ? Wq : (wave == 1) ? Wk : Wv;
    float wreg[64];
    #pragma unroll
    for (int j = 0; j < 16; ++j) {
        float4 w4 = *(const float4*)(Wsel + lane * 64 + j * 4);
        wreg[j*4+0] = w4.x; wreg[j*4+1] = w4.y; wreg[j*4+2] = w4.z; wreg[j*4+3] = w4.w;
    }

    const int r  = t >> 4;   // 0..11  (staging row)
    const int c4 = t & 15;   // 0..15  (staging float4 col)

    for (int wi = 0; wi < WPB; ++wi) {
        const int n = seg * WPB + wi;
        if (n >= NW) break;

        // --- stage X: 12 rows x 64 floats x 3 inputs, one float4 per thread per input ---
        {
            const int l = n * STEP_ + r;
            const size_t base = (((size_t)b * L_ + l) * H_ + h) * DH + c4 * 4;
            *(float4*)&Xs[0][r][c4 * 4] = *(const float4*)(q + base);
            *(float4*)&Xs[1][r][c4 * 4] = *(const float4*)(k + base);
            *(float4*)&Xs[2][r][c4 * 4] = *(const float4*)(v + base);
        }
        __syncthreads();

        // --- projection: wave p, lane e: Ps[p][w][e] = dot(X_p[w][:], W_p[e][:]) ---
        for (int w = 0; w < WS_; ++w) {
            float acc = 0.f;
            #pragma unroll
            for (int j = 0; j < 16; ++j) {
                float4 x4 = *(const float4*)&Xs[wave][w][j * 4];   // wave-uniform broadcast
                acc = fmaf(x4.x, wreg[j*4+0], acc);
                acc = fmaf(x4.y, wreg[j*4+1], acc);
                acc = fmaf(x4.z, wreg[j*4+2], acc);
                acc = fmaf(x4.w, wreg[j*4+3], acc);
            }
            Ps[wave][w][lane] = acc;
        }
        __syncthreads();

        // --- scores: S[wq][wk] = (Q[wq].K[wk]) / 8 ; 144 entries over threads 0..143 ---
        if (t < WS_ * WS_) {
            const int wq = t / WS_, wk = t - wq * WS_;
            float s = 0.f;
            #pragma unroll
            for (int j = 0; j < 16; ++j) {
                float4 q4 = *(const float4*)&Ps[0][wq][j * 4];
                float4 k4 = *(const float4*)&Ps[1][wk][j * 4];
                s = fmaf(q4.x, k4.x, s);
                s = fmaf(q4.y, k4.y, s);
                s = fmaf(q4.z, k4.z, s);
                s = fmaf(q4.w, k4.w, s);
            }
            P[wq][wk] = s * 0.125f;
        }
        __syncthreads();

        // --- softmax per row (12 rows) ---
        if (t < WS_) {
            float mx = -1e30f;
            #pragma unroll
            for (int j = 0; j < WS_; ++j) mx = fmaxf(mx, P[t][j]);
            float sum = 0.f;
            #pragma unroll
            for (int j = 0; j < WS_; ++j) { float e = __expf(P[t][j] - mx); P[t][j] = e; sum += e; }
            const float inv = 1.0f / sum;
            #pragma unroll
            for (int j = 0; j < WS_; ++j) P[t][j] *= inv;
        }
        __syncthreads();

        // --- write attn probabilities ---
        if (t < WS_ * WS_) {
            attn_out[(((size_t)b * H_ + h) * NW + n) * (WS_ * WS_) + t] = P[t / WS_][t % WS_];
        }

        // --- P @ V -> ow : 768 outputs over 192 threads (4 each) ---
        float* owp = ow_ws + (((size_t)b * H_ + h) * NW + n) * (WS_ * DH);
        #pragma unroll
        for (int s = 0; s < 4; ++s) {
            const int idx = t + s * 192;          // 0..767
            const int w = idx >> 6, e = idx & 63; // w uniform per (wave,s) -> P broadcast
            float acc = 0.f;
            #pragma unroll
            for (int kk = 0; kk < WS_; ++kk)
                acc = fmaf(P[w][kk], Ps[2][kk][e], acc);
            owp[w * DH + e] = acc;
        }
        __syncthreads();   // protect Xs/Ps/P before next window's staging
    }
}

// ---------------------------------------------------------------------------
// Gather overlap-add (<=2 windows per row, deterministic) + 1/cnt + residual
// + LayerNorm. One block of 128 threads per (b,l) row; float4 per thread.
// ---------------------------------------------------------------------------
__global__ __launch_bounds__(128) void oadd_ln_kernel(
    const float* __restrict__ ow_ws, const float* __restrict__ q,
    const float* __restrict__ gamma, const float* __restrict__ beta,
    float* __restrict__ z)
{
    const int row = blockIdx.x;          // b*L + l
    const int b = row / L_;
    const int l = row - b * L_;
    const int t = threadIdx.x;           // 0..127
    const int c = t * 4;                 // 0..508
    const int h = c >> 6;
    const int e = c & 63;

    const int nA = l / STEP_;            // later window (may be == NW, invalid)
    const int nB = nA - 1;               // earlier window (may be -1, invalid)
    const bool vA = (nA < NW);
    const bool vB = (nB >= 0);
    const float cntInv = 1.0f / (float)((vA ? 1 : 0) + (vB ? 1 : 0));

    float4 s = make_float4(0.f, 0.f, 0.f, 0.f);
    if (vA) {
        const int w = l - nA * STEP_;
        float4 a = *(const float4*)(ow_ws + ((((size_t)b * H_ + h) * NW + nA) * WS_ + w) * DH + e);
        s.x += a.x; s.y += a.y; s.z += a.z; s.w += a.w;
    }
    if (vB) {
        const int w = l - nB * STEP_;
        float4 a = *(const float4*)(ow_ws + ((((size_t)b * H_ + h) * NW + nB) * WS_ + w) * DH + e);
        s.x += a.x; s.y += a.y; s.z += a.z; s.w += a.w;
    }
    const float4 r4 = *(const float4*)(q + (size_t)row * DM + c);
    float4 x;
    x.x = s.x * cntInv + r4.x;
    x.y = s.y * cntInv + r4.y;
    x.z = s.z * cntInv + r4.z;
    x.w = s.w * cntInv + r4.w;

    float s1 = x.x + x.y + x.z + x.w;
    float s2 = x.x*x.x + x.y*x.y + x.z*x.z + x.w*x.w;
    #pragma unroll
    for (int off = 32; off > 0; off >>= 1) {
        s1 += __shfl_down(s1, off);
        s2 += __shfl_down(s2, off);
    }
    __shared__ float r1[2], r2[2];
    const int wid = t >> 6;
    if ((t & 63) == 0) { r1[wid] = s1; r2[wid] = s2; }
    __syncthreads();
    s1 = r1[0] + r1[1];
    s2 = r2[0] + r2[1];
    const float mu  = s1 * (1.0f / 512.0f);
    const float var = s2 * (1.0f / 512.0f) - mu * mu;
    const float inv = 1.0f / sqrtf(var + EPS_);

    const float4 g4 = *(const float4*)(gamma + c);
    const float4 b4 = *(const float4*)(beta + c);
    float4 o;
    o.x = (x.x - mu) * inv * g4.x + b4.x;
    o.y = (x.y - mu) * inv * g4.y + b4.y;
    o.z = (x.z - mu) * inv * g4.z + b4.z;
    o.w = (x.w - mu) * inv * g4.w + b4.w;
    *(float4*)(z + (size_t)row * DM + c) = o;
}

extern "C" void kernel_launch(void* const* d_in, const int* in_sizes, int n_in,
                              void* d_out, int out_size, void* d_ws, size_t ws_size,
                              hipStream_t stream) {
    const float* q     = (const float*)d_in[0];
    const float* k     = (const float*)d_in[1];
    const float* v     = (const float*)d_in[2];
    const float* Wq    = (const float*)d_in[3];
    const float* Wk    = (const float*)d_in[4];
    const float* Wv    = (const float*)d_in[5];
    const float* gamma = (const float*)d_in[6];
    const float* beta  = (const float*)d_in[7];

    float* z    = (float*)d_out;
    float* attn = (float*)d_out + Z_ELEMS;
    float* ow   = (float*)d_ws;   // B*H*NW*WS*DH fp32 = ~67 MB

    fused_attn_kernel<<<dim3(NSEG, H_, B_), 192, 0, stream>>>(q, k, v, Wq, Wk, Wv, attn, ow);
    oadd_ln_kernel<<<B_ * L_, 128, 0, stream>>>(ow, q, gamma, beta, z);
}

// Round 3
// 213.885 us; speedup vs baseline: 3.2185x; 1.6551x over previous
//
#include <hip/hip_runtime.h>
#include <math.h>

#define B_    4
#define L_    4092
#define H_    8
#define DH    64
#define DM    512
#define WS_   12
#define STEP_ 6
#define NW    681
#define NC    682            // output chunks of 6 rows per (b,h)
#define EPS_  1e-5f
#define Z_ELEMS (B_*L_*DM)   // 8,380,416

typedef __attribute__((ext_vector_type(8))) short short8;
typedef __attribute__((ext_vector_type(4))) float floatx4;
typedef unsigned short u16;

__device__ __forceinline__ u16 f2bf(float f) {
    union { float f; unsigned u; } x; x.f = f;
    unsigned u = x.u;
    return (u16)((u + 0x7FFFu + ((u >> 16) & 1u)) >> 16);
}
__device__ __forceinline__ short8 pack8(float4 a, float4 b) {
    short8 r;
    r[0] = (short)f2bf(a.x); r[1] = (short)f2bf(a.y);
    r[2] = (short)f2bf(a.z); r[3] = (short)f2bf(a.w);
    r[4] = (short)f2bf(b.x); r[5] = (short)f2bf(b.y);
    r[6] = (short)f2bf(b.z); r[7] = (short)f2bf(b.w);
    return r;
}

// ---------------------------------------------------------------------------
// K1: projection GEMM. rows r = (b*H+h)*L + l (130,944 = 8184 tiles of 16).
// A = X rows (fp32->bf16), B = W^T (lane n holds W[n][k-chunk]), D -> Yp bf16
// layout [b,h,l,64]. Grid (512, 3): blockIdx.y selects tensor.
// ---------------------------------------------------------------------------
__global__ __launch_bounds__(256) void proj_kernel(
    const float* __restrict__ q, const float* __restrict__ k, const float* __restrict__ v,
    const float* __restrict__ Wq, const float* __restrict__ Wk, const float* __restrict__ Wv,
    u16* __restrict__ Qp, u16* __restrict__ Kp, u16* __restrict__ Vp)
{
    const int tensor = blockIdx.y;
    const float* __restrict__ X = (tensor == 0) ? q  : (tensor == 1) ? k  : v;
    const float* __restrict__ W = (tensor == 0) ? Wq : (tensor == 1) ? Wk : Wv;
    u16* __restrict__ Y         = (tensor == 0) ? Qp : (tensor == 1) ? Kp : Vp;

    const int t = threadIdx.x, lane = t & 63, wv = t >> 6;
    const int m = lane & 15, q3 = lane >> 4;

    // preload W B-frags: wf[nt][kc]; B[k][n] = W[n][k]; lane n=m holds 8 consecutive k
    short8 wf[4][2];
    #pragma unroll
    for (int nt = 0; nt < 4; ++nt)
        #pragma unroll
        for (int kc = 0; kc < 2; ++kc) {
            const float* wp = W + (nt * 16 + m) * 64 + kc * 32 + q3 * 8;
            wf[nt][kc] = pack8(*(const float4*)wp, *(const float4*)(wp + 4));
        }

    const int waveId = blockIdx.x * 4 + wv;        // 0..2047
    for (int tile = waveId; tile < 8184; tile += 2048) {
        const int rbase = tile * 16;
        // A-frag: row = rbase + m, k = kc*32 + q3*8 + j
        const int r = rbase + m;
        const int bh = r / L_;
        const int l = r - bh * L_;
        const int b = bh >> 3, h = bh & 7;
        const float* xp = X + (((size_t)b * L_ + l) * H_ + h) * 64;
        short8 a0 = pack8(*(const float4*)(xp + q3 * 8),      *(const float4*)(xp + q3 * 8 + 4));
        short8 a1 = pack8(*(const float4*)(xp + 32 + q3 * 8), *(const float4*)(xp + 32 + q3 * 8 + 4));

        floatx4 acc[4];
        #pragma unroll
        for (int nt = 0; nt < 4; ++nt) {
            floatx4 c = {0.f, 0.f, 0.f, 0.f};
            c = __builtin_amdgcn_mfma_f32_16x16x32_bf16(a0, wf[nt][0], c, 0, 0, 0);
            c = __builtin_amdgcn_mfma_f32_16x16x32_bf16(a1, wf[nt][1], c, 0, 0, 0);
            acc[nt] = c;
        }
        // D: row = rbase + q3*4 + reg, col = nt*16 + m
        #pragma unroll
        for (int reg = 0; reg < 4; ++reg) {
            const size_t rowoff = (size_t)(rbase + q3 * 4 + reg) * 64;
            #pragma unroll
            for (int nt = 0; nt < 4; ++nt)
                Y[rowoff + nt * 16 + m] = f2bf(acc[nt][reg]);
        }
    }
}

// ---------------------------------------------------------------------------
// K2: per-wave window attention + overlap-add. Wave handles chunk c (6 rows):
// windows wA=c, wB=c-1 via MFMA; softmax in C-layout; P relayout via wave-
// private LDS; PV K=32 zero-padded. Writes attn (window c) + pre-LN z rows.
// No __syncthreads anywhere.
// ---------------------------------------------------------------------------
__device__ __forceinline__ void window_attn(
    const u16* __restrict__ Qb, const u16* __restrict__ Kb, const u16* __restrict__ Vb,
    float* __restrict__ attn_out /*may be null*/, float* __restrict__ Pl,
    int w, int lane, floatx4 o[4])
{
    const int m = lane & 15, q3 = lane >> 4;
    const size_t rb = (size_t)(w * 6 + m) * 64;

    short8 aq0 = *(const short8*)(Qb + rb + q3 * 8);
    short8 aq1 = *(const short8*)(Qb + rb + 32 + q3 * 8);
    short8 bk0 = *(const short8*)(Kb + rb + q3 * 8);
    short8 bk1 = *(const short8*)(Kb + rb + 32 + q3 * 8);

    floatx4 s4 = {0.f, 0.f, 0.f, 0.f};
    s4 = __builtin_amdgcn_mfma_f32_16x16x32_bf16(aq0, bk0, s4, 0, 0, 0);
    s4 = __builtin_amdgcn_mfma_f32_16x16x32_bf16(aq1, bk1, s4, 0, 0, 0);

    // softmax per row (row = q3*4+reg, col = m); mask cols >= 12
    float p[4];
    #pragma unroll
    for (int r = 0; r < 4; ++r) {
        float s = (m < 12) ? s4[r] * 0.125f : -1e30f;
        float mx = s;
        #pragma unroll
        for (int off = 1; off < 16; off <<= 1)
            mx = fmaxf(mx, __shfl_xor(mx, off, 16));
        float e = __expf(s - mx);
        float sum = e;
        #pragma unroll
        for (int off = 1; off < 16; off <<= 1)
            sum += __shfl_xor(sum, off, 16);
        p[r] = e / sum;
    }

    if (attn_out && m < 12 && q3 < 3) {
        #pragma unroll
        for (int r = 0; r < 4; ++r)
            attn_out[(q3 * 4 + r) * 12 + m] = p[r];
    }

    // P (C-layout) -> LDS [16][20] -> A-frag layout
    #pragma unroll
    for (int r = 0; r < 4; ++r)
        Pl[(q3 * 4 + r) * 20 + m] = p[r];
    short8 ap = {0, 0, 0, 0, 0, 0, 0, 0};
    if (q3 < 2) {
        float4 f0 = *(const float4*)&Pl[m * 20 + q3 * 8];
        float4 f1 = *(const float4*)&Pl[m * 20 + q3 * 8 + 4];
        ap = pack8(f0, f1);
    }

    // PV: B[k=j][n=e], k = q3*8+jj; j>=12 values multiply p=0 (safe garbage)
    const int w6 = w * 6;
    #pragma unroll
    for (int nt = 0; nt < 4; ++nt) {
        short8 bv;
        #pragma unroll
        for (int jj = 0; jj < 8; ++jj)
            bv[jj] = (short)Vb[(size_t)(w6 + q3 * 8 + jj) * 64 + nt * 16 + m];
        floatx4 oo = {0.f, 0.f, 0.f, 0.f};
        oo = __builtin_amdgcn_mfma_f32_16x16x32_bf16(ap, bv, oo, 0, 0, 0);
        o[nt] = oo;
    }
}

__global__ __launch_bounds__(256) void attn_kernel(
    const u16* __restrict__ Qp, const u16* __restrict__ Kp, const u16* __restrict__ Vp,
    float* __restrict__ attn, float* __restrict__ z)
{
    __shared__ float P_lds[4][16 * 20];
    __shared__ float Oacc[4][6 * 64];
    const int t = threadIdx.x, lane = t & 63, wv = t >> 6;
    const int m = lane & 15, q3 = lane >> 4;
    const int c = blockIdx.x * 4 + wv;
    const int h = blockIdx.y, b = blockIdx.z;
    if (c >= NC) return;
    const int bh = b * H_ + h;
    const u16* Qb = Qp + (size_t)bh * L_ * 64;
    const u16* Kb = Kp + (size_t)bh * L_ * 64;
    const u16* Vb = Vp + (size_t)bh * L_ * 64;
    float* Pl = P_lds[wv];
    float* Oa = Oacc[wv];
    const bool hasA = (c < NW), hasB = (c > 0);
    const float scale = (hasA && hasB) ? 0.5f : 1.0f;

    floatx4 oA[4], oB[4];
    if (hasA) {
        float* ao = attn + ((size_t)bh * NW + c) * (WS_ * WS_);
        window_attn(Qb, Kb, Vb, ao, Pl, c, lane, oA);
        if (hasB) {
            // stash chunk rows 0..5 (window A rows 0..5) in LDS
            #pragma unroll
            for (int r = 0; r < 4; ++r) {
                const int row = q3 * 4 + r;
                if (row < 6) {
                    #pragma unroll
                    for (int nt = 0; nt < 4; ++nt)
                        Oa[row * 64 + nt * 16 + m] = oA[nt][r];
                }
            }
        } else {
            // c == 0: cnt = 1, direct store
            #pragma unroll
            for (int r = 0; r < 4; ++r) {
                const int row = q3 * 4 + r;
                if (row < 6) {
                    #pragma unroll
                    for (int nt = 0; nt < 4; ++nt)
                        z[((size_t)b * L_ + row) * DM + h * 64 + nt * 16 + m] = oA[nt][r];
                }
            }
        }
    }
    if (hasB) {
        window_attn(Qb, Kb, Vb, nullptr, Pl, c - 1, lane, oB);
        // window B rows 6..11 are chunk rows 0..5
        #pragma unroll
        for (int r = 0; r < 4; ++r) {
            const int row = q3 * 4 + r;
            if (row >= 6 && row < 12) {
                const int rr = row - 6;
                #pragma unroll
                for (int nt = 0; nt < 4; ++nt) {
                    float val = oB[nt][r];
                    if (hasA) val += Oa[rr * 64 + nt * 16 + m];
                    z[((size_t)b * L_ + c * 6 + rr) * DM + h * 64 + nt * 16 + m] = val * scale;
                }
            }
        }
    }
}

// ---------------------------------------------------------------------------
// K3: in-place residual + LayerNorm on z. 2 rows per 256-thread block.
// ---------------------------------------------------------------------------
__global__ __launch_bounds__(256) void ln_kernel(
    const float* __restrict__ qres, const float* __restrict__ gamma,
    const float* __restrict__ beta, float* __restrict__ z)
{
    const int t = threadIdx.x;
    const int rr = t >> 7;               // 0..1
    const int tt = t & 127;
    const size_t row = (size_t)blockIdx.x * 2 + rr;
    const int c = tt * 4;

    float4 a  = *(const float4*)(z + row * DM + c);
    float4 r4 = *(const float4*)(qres + row * DM + c);
    float4 x = make_float4(a.x + r4.x, a.y + r4.y, a.z + r4.z, a.w + r4.w);

    float s1 = x.x + x.y + x.z + x.w;
    float s2 = x.x * x.x + x.y * x.y + x.z * x.z + x.w * x.w;
    #pragma unroll
    for (int off = 1; off < 64; off <<= 1) {
        s1 += __shfl_xor(s1, off, 64);
        s2 += __shfl_xor(s2, off, 64);
    }
    __shared__ float red[4][2];
    const int wid = t >> 6;
    if ((t & 63) == 0) { red[wid][0] = s1; red[wid][1] = s2; }
    __syncthreads();
    const int wp = wid & 2;
    s1 = red[wp][0] + red[wp + 1][0];
    s2 = red[wp][1] + red[wp + 1][1];
    const float mu  = s1 * (1.0f / 512.0f);
    const float var = s2 * (1.0f / 512.0f) - mu * mu;
    const float inv = 1.0f / sqrtf(var + EPS_);

    float4 g4 = *(const float4*)(gamma + c);
    float4 b4 = *(const float4*)(beta + c);
    float4 o;
    o.x = (x.x - mu) * inv * g4.x + b4.x;
    o.y = (x.y - mu) * inv * g4.y + b4.y;
    o.z = (x.z - mu) * inv * g4.z + b4.z;
    o.w = (x.w - mu) * inv * g4.w + b4.w;
    *(float4*)(z + row * DM + c) = o;
}

extern "C" void kernel_launch(void* const* d_in, const int* in_sizes, int n_in,
                              void* d_out, int out_size, void* d_ws, size_t ws_size,
                              hipStream_t stream) {
    const float* q     = (const float*)d_in[0];
    const float* k     = (const float*)d_in[1];
    const float* v     = (const float*)d_in[2];
    const float* Wq    = (const float*)d_in[3];
    const float* Wk    = (const float*)d_in[4];
    const float* Wv    = (const float*)d_in[5];
    const float* gamma = (const float*)d_in[6];
    const float* beta  = (const float*)d_in[7];

    float* z    = (float*)d_out;
    float* attn = (float*)d_out + Z_ELEMS;

    u16* Qp = (u16*)d_ws;                       // [b,h,l,64] bf16
    u16* Kp = Qp + (size_t)B_ * H_ * L_ * 64;   // + 8,380,416
    u16* Vp = Kp + (size_t)B_ * H_ * L_ * 64;   // total 50.3 MB

    proj_kernel<<<dim3(512, 3, 1), 256, 0, stream>>>(q, k, v, Wq, Wk, Wv, Qp, Kp, Vp);
    attn_kernel<<<dim3((NC + 3) / 4, H_, B_), 256, 0, stream>>>(Qp, Kp, Vp, attn, z);
    ln_kernel<<<(B_ * L_) / 2, 256, 0, stream>>>(q, gamma, beta, z);
}

// Round 5
// 203.292 us; speedup vs baseline: 3.3862x; 1.0521x over previous
//
#include <hip/hip_runtime.h>
#include <math.h>

#define B_    4
#define L_    4092
#define H_    8
#define DH    64
#define DM    512
#define WS_   12
#define STEP_ 6
#define NW    681
#define NC    682            // 6-row output chunks per (b,h); L = 6*682
#define EPS_  1e-5f
#define Z_ELEMS (B_*L_*DM)   // 8,380,416

typedef __attribute__((ext_vector_type(8))) short short8;
typedef __attribute__((ext_vector_type(4))) float floatx4;
typedef unsigned short u16;

__device__ __forceinline__ u16 f2bf(float f) {
    union { float f; unsigned u; } x; x.f = f;
    unsigned u = x.u;
    return (u16)((u + 0x7FFFu + ((u >> 16) & 1u)) >> 16);
}
__device__ __forceinline__ short8 pack8(float4 a, float4 b) {
    short8 r;
    r[0] = (short)f2bf(a.x); r[1] = (short)f2bf(a.y);
    r[2] = (short)f2bf(a.z); r[3] = (short)f2bf(a.w);
    r[4] = (short)f2bf(b.x); r[5] = (short)f2bf(b.y);
    r[6] = (short)f2bf(b.z); r[7] = (short)f2bf(b.w);
    return r;
}

// ---------------------------------------------------------------------------
// K1: projection GEMM, rows r=(b*H+h)*L+l (130,944 = 8184 tiles of 16).
// B-frag nt holds W rows 4m+nt  =>  lane m's 4 accs are cols 4m..4m+3
// => ushort4 (8B) stores, 4 per lane per tile.
// ---------------------------------------------------------------------------
__global__ __launch_bounds__(256) void proj_kernel(
    const float* __restrict__ q, const float* __restrict__ k, const float* __restrict__ v,
    const float* __restrict__ Wq, const float* __restrict__ Wk, const float* __restrict__ Wv,
    u16* __restrict__ Qp, u16* __restrict__ Kp, u16* __restrict__ Vp)
{
    const int tensor = blockIdx.y;
    const float* __restrict__ X = (tensor == 0) ? q  : (tensor == 1) ? k  : v;
    const float* __restrict__ W = (tensor == 0) ? Wq : (tensor == 1) ? Wk : Wv;
    u16* __restrict__ Y         = (tensor == 0) ? Qp : (tensor == 1) ? Kp : Vp;

    const int t = threadIdx.x, lane = t & 63, wv = t >> 6;
    const int m = lane & 15, q3 = lane >> 4;

    short8 wf[4][2];
    #pragma unroll
    for (int nt = 0; nt < 4; ++nt)
        #pragma unroll
        for (int kc = 0; kc < 2; ++kc) {
            const float* wp = W + (4 * m + nt) * 64 + kc * 32 + q3 * 8;
            wf[nt][kc] = pack8(*(const float4*)wp, *(const float4*)(wp + 4));
        }

    const int waveId = blockIdx.x * 4 + wv;        // 0..2047
    for (int tile = waveId; tile < 8184; tile += 2048) {
        const int rbase = tile * 16;
        const int r = rbase + m;
        const int bh = r / L_;
        const int l = r - bh * L_;
        const int b = bh >> 3, h = bh & 7;
        const float* xp = X + (((size_t)b * L_ + l) * H_ + h) * 64;
        short8 a0 = pack8(*(const float4*)(xp + q3 * 8),      *(const float4*)(xp + q3 * 8 + 4));
        short8 a1 = pack8(*(const float4*)(xp + 32 + q3 * 8), *(const float4*)(xp + 32 + q3 * 8 + 4));

        floatx4 acc[4];
        #pragma unroll
        for (int nt = 0; nt < 4; ++nt) {
            floatx4 c = {0.f, 0.f, 0.f, 0.f};
            c = __builtin_amdgcn_mfma_f32_16x16x32_bf16(a0, wf[nt][0], c, 0, 0, 0);
            c = __builtin_amdgcn_mfma_f32_16x16x32_bf16(a1, wf[nt][1], c, 0, 0, 0);
            acc[nt] = c;
        }
        #pragma unroll
        for (int reg = 0; reg < 4; ++reg) {
            const int row = rbase + q3 * 4 + reg;
            ushort4 o4;
            o4.x = f2bf(acc[0][reg]); o4.y = f2bf(acc[1][reg]);
            o4.z = f2bf(acc[2][reg]); o4.w = f2bf(acc[3][reg]);
            *(ushort4*)(Y + (size_t)row * 64 + 4 * m) = o4;
        }
    }
}

// ---------------------------------------------------------------------------
// K2: fused window attention + overlap-add + residual + LayerNorm.
// Block = 512 threads (wave = head) per (b, chunk c). V staged in LDS.
// NOTE: every cross-lane LDS handoff is protected by __syncthreads() —
// per-thread addresses don't overlap, so without a barrier the compiler may
// legally reorder the read before the write (R4's nondeterminism bug).
// All barriers are block-uniform (hasA/hasB depend only on blockIdx).
// ---------------------------------------------------------------------------
__device__ __forceinline__ void window_attn(
    const u16* __restrict__ Qb, const u16* __restrict__ Kb, const u16* __restrict__ VsH,
    float* __restrict__ attn_out /*or null*/, float* __restrict__ PlF,
    int w, int off, int lane, floatx4 o[4])
{
    const int m = lane & 15, q3 = lane >> 4;
    const size_t rb = (size_t)(w * 6 + m) * 64;

    short8 aq0 = *(const short8*)(Qb + rb + q3 * 8);
    short8 aq1 = *(const short8*)(Qb + rb + 32 + q3 * 8);
    short8 bk0 = *(const short8*)(Kb + rb + q3 * 8);
    short8 bk1 = *(const short8*)(Kb + rb + 32 + q3 * 8);

    floatx4 s4 = {0.f, 0.f, 0.f, 0.f};
    s4 = __builtin_amdgcn_mfma_f32_16x16x32_bf16(aq0, bk0, s4, 0, 0, 0);
    s4 = __builtin_amdgcn_mfma_f32_16x16x32_bf16(aq1, bk1, s4, 0, 0, 0);

    // softmax per row (row = q3*4+reg, col = m); mask cols >= 12
    float p[4];
    #pragma unroll
    for (int r = 0; r < 4; ++r) {
        float s = (m < 12) ? s4[r] * 0.125f : -1e30f;
        float mx = s;
        #pragma unroll
        for (int o2 = 1; o2 < 16; o2 <<= 1)
            mx = fmaxf(mx, __shfl_xor(mx, o2, 16));
        float e = __expf(s - mx);
        float sum = e;
        #pragma unroll
        for (int o2 = 1; o2 < 16; o2 <<= 1)
            sum += __shfl_xor(sum, o2, 16);
        p[r] = e / sum;
    }

    if (attn_out && m < 12 && q3 < 3) {
        #pragma unroll
        for (int r = 0; r < 4; ++r)
            attn_out[(q3 * 4 + r) * 12 + m] = p[r];
    }

    // P (C-layout, fp32) -> LDS [16][20] -> A-frag; barrier makes the
    // cross-lane handoff visible & compiler-safe.
    #pragma unroll
    for (int r = 0; r < 4; ++r)
        PlF[(q3 * 4 + r) * 20 + m] = p[r];
    __syncthreads();
    short8 ap = {0, 0, 0, 0, 0, 0, 0, 0};
    if (q3 < 2) {
        float4 f0 = *(const float4*)&PlF[m * 20 + q3 * 8];
        float4 f1 = *(const float4*)&PlF[m * 20 + q3 * 8 + 4];
        ap = pack8(f0, f1);
    }

    // PV: B-frag lane m holds V[off + k][nt*16+m], k = q3*8+jj; k>=12 -> 0 (p=0 there)
    #pragma unroll
    for (int nt = 0; nt < 4; ++nt) {
        short8 bv = {0, 0, 0, 0, 0, 0, 0, 0};
        if (q3 == 0) {
            #pragma unroll
            for (int jj = 0; jj < 8; ++jj)
                bv[jj] = (short)VsH[(off + jj) * 64 + nt * 16 + m];
        } else if (q3 == 1) {
            #pragma unroll
            for (int jj = 0; jj < 4; ++jj)
                bv[jj] = (short)VsH[(off + 8 + jj) * 64 + nt * 16 + m];
        }
        floatx4 oo = {0.f, 0.f, 0.f, 0.f};
        oo = __builtin_amdgcn_mfma_f32_16x16x32_bf16(ap, bv, oo, 0, 0, 0);
        o[nt] = oo;
    }
}

__global__ __launch_bounds__(512) void attn_ln_kernel(
    const u16* __restrict__ Qp, const u16* __restrict__ Kp, const u16* __restrict__ Vp,
    const float* __restrict__ qres, const float* __restrict__ gamma,
    const float* __restrict__ beta, float* __restrict__ attn, float* __restrict__ z)
{
    __shared__ alignas(16) u16   Vs[8][18][64];     // 18.4 KB
    __shared__ alignas(16) float Pl[8][16 * 20];    // 10.2 KB
    __shared__ alignas(16) float Xs[6][512];        // 12.3 KB

    const int c = blockIdx.x, b = blockIdx.y;
    const int t = threadIdx.x, lane = t & 63, h = t >> 6;
    const int m = lane & 15, q3 = lane >> 4;

    // --- stage V: 8 heads x 18 rows x 64 cols (bounds-checked), ushort4 loads ---
    const int lbase = c * 6 - 6;
    for (int i = t; i < 2304; i += 512) {            // 2304 = 8*18*16 ushort4
        const int hh  = i / 288;
        const int rem = i - hh * 288;
        const int rr  = rem >> 4;
        const int cc  = (rem & 15) * 4;
        const int l = lbase + rr;
        if (l >= 0 && l < L_)
            *(ushort4*)&Vs[hh][rr][cc] =
                *(const ushort4*)(Vp + ((size_t)(b * 8 + hh) * L_ + l) * 64 + cc);
    }
    __syncthreads();

    const int bh = b * 8 + h;
    const u16* Qb = Qp + (size_t)bh * L_ * 64;
    const u16* Kb = Kp + (size_t)bh * L_ * 64;
    const u16* VsH = &Vs[h][0][0];
    float* PlH = &Pl[h][0];

    const bool hasA = (c < NW), hasB = (c > 0);     // block-uniform
    const float scale = (hasA && hasB) ? 0.5f : 1.0f;

    floatx4 oA[4], oB[4];
    if (hasA) {
        float* ao = attn + ((size_t)bh * NW + c) * (WS_ * WS_);
        window_attn(Qb, Kb, VsH, ao, PlH, c, 6, lane, oA);
        // window A rows 0..5 are this chunk's rows 0..5 -> stash in Xs
        #pragma unroll
        for (int r = 0; r < 4; ++r) {
            const int row = q3 * 4 + r;
            if (row < 6) {
                #pragma unroll
                for (int nt = 0; nt < 4; ++nt)
                    Xs[row][h * 64 + nt * 16 + m] = oA[nt][r];
            }
        }
    }
    __syncthreads();   // Xs stash visible; Pl call-A reads done before call-B writes
    if (hasB) {
        window_attn(Qb, Kb, VsH, nullptr, PlH, c - 1, 0, lane, oB);
        // window B rows 6..11 are this chunk's rows 0..5
        #pragma unroll
        for (int r = 0; r < 4; ++r) {
            const int row = q3 * 4 + r;
            if (row >= 6 && row < 12) {
                const int rr = row - 6;
                #pragma unroll
                for (int nt = 0; nt < 4; ++nt) {
                    float val = oB[nt][r];
                    if (hasA) val += Xs[rr][h * 64 + nt * 16 + m];
                    Xs[rr][h * 64 + nt * 16 + m] = val * scale;
                }
            }
        }
    }
    __syncthreads();

    // --- LN: wave w (<6) handles chunk row w; lane covers 8 cols ---
    if (h < 6) {
        const int l = c * 6 + h;                       // < L always (L = 6*682)
        const int cc = lane * 8;
        float4 xa = *(const float4*)&Xs[h][cc];
        float4 xb = *(const float4*)&Xs[h][cc + 4];
        const float* qr = qres + ((size_t)b * L_ + l) * DM + cc;
        const float4 ra = *(const float4*)qr;
        const float4 rb2 = *(const float4*)(qr + 4);
        xa.x += ra.x;  xa.y += ra.y;  xa.z += ra.z;  xa.w += ra.w;
        xb.x += rb2.x; xb.y += rb2.y; xb.z += rb2.z; xb.w += rb2.w;

        float s1 = xa.x + xa.y + xa.z + xa.w + xb.x + xb.y + xb.z + xb.w;
        float s2 = xa.x*xa.x + xa.y*xa.y + xa.z*xa.z + xa.w*xa.w
                 + xb.x*xb.x + xb.y*xb.y + xb.z*xb.z + xb.w*xb.w;
        #pragma unroll
        for (int off = 1; off < 64; off <<= 1) {
            s1 += __shfl_xor(s1, off, 64);
            s2 += __shfl_xor(s2, off, 64);
        }
        const float mu  = s1 * (1.0f / 512.0f);
        const float var = s2 * (1.0f / 512.0f) - mu * mu;
        const float inv = 1.0f / sqrtf(var + EPS_);

        const float4 ga = *(const float4*)(gamma + cc);
        const float4 gb = *(const float4*)(gamma + cc + 4);
        const float4 ba = *(const float4*)(beta + cc);
        const float4 bb = *(const float4*)(beta + cc + 4);
        float4 oa, ob;
        oa.x = (xa.x - mu) * inv * ga.x + ba.x;
        oa.y = (xa.y - mu) * inv * ga.y + ba.y;
        oa.z = (xa.z - mu) * inv * ga.z + ba.z;
        oa.w = (xa.w - mu) * inv * ga.w + ba.w;
        ob.x = (xb.x - mu) * inv * gb.x + bb.x;
        ob.y = (xb.y - mu) * inv * gb.y + bb.y;
        ob.z = (xb.z - mu) * inv * gb.z + bb.z;
        ob.w = (xb.w - mu) * inv * gb.w + bb.w;
        float* zp = z + ((size_t)b * L_ + l) * DM + cc;
        *(float4*)zp = oa;
        *(float4*)(zp + 4) = ob;
    }
}

extern "C" void kernel_launch(void* const* d_in, const int* in_sizes, int n_in,
                              void* d_out, int out_size, void* d_ws, size_t ws_size,
                              hipStream_t stream) {
    const float* q     = (const float*)d_in[0];
    const float* k     = (const float*)d_in[1];
    const float* v     = (const float*)d_in[2];
    const float* Wq    = (const float*)d_in[3];
    const float* Wk    = (const float*)d_in[4];
    const float* Wv    = (const float*)d_in[5];
    const float* gamma = (const float*)d_in[6];
    const float* beta  = (const float*)d_in[7];

    float* z    = (float*)d_out;
    float* attn = (float*)d_out + Z_ELEMS;

    u16* Qp = (u16*)d_ws;                       // [b,h,l,64] bf16
    u16* Kp = Qp + (size_t)B_ * H_ * L_ * 64;
    u16* Vp = Kp + (size_t)B_ * H_ * L_ * 64;   // total 50.3 MB

    proj_kernel<<<dim3(512, 3, 1), 256, 0, stream>>>(q, k, v, Wq, Wk, Wv, Qp, Kp, Vp);
    attn_ln_kernel<<<dim3(NC, B_), 512, 0, stream>>>(Qp, Kp, Vp, q, gamma, beta, attn, z);
}